// Round 9
// baseline (157.883 us; speedup 1.0000x reference)
//
#include <hip/hip_runtime.h>

#define NCTX 3
#define B 8
#define CC 128
#define CF 256
#define H 64
#define W 64
#define HW 4096
#define YX 16384   // (2H)*(2W)

// workspace layout (float offsets)
#define WS_QT    0          // bf16 qtB: B*CC*HW ushorts
#define WS_VALS  4194304    // bf16 valsB: B*CC*HW ushorts
#define WS_BIAS  8388608    // bias448 (448 floats)
#define WS_LM    8421376    // B*HW
#define WS_WALL  8454144    // bf16 Wall hi: 8*4*448*8 = 114688 ushorts
#define WS_MSP   8552960    // bf16 msP hi: 8*66*32*66*8 = 8921088 ushorts
#define WS_WB    13013504   // bf16 Wb: 9*8*4*128*8 = 294912 ushorts
#define WS_WALLO 13160960   // bf16 Wall lo: 114688 ushorts (end 13218304)

typedef __attribute__((ext_vector_type(8))) short bf16x8;
typedef __attribute__((ext_vector_type(4))) float f32x4;
typedef __attribute__((ext_vector_type(8))) unsigned short u16x8;

__device__ __forceinline__ unsigned short f2b(float f) {
    union { float f; unsigned u; } c; c.f = f;
    unsigned u = c.u + 0x7FFFu + ((c.u >> 16) & 1u);
    return (unsigned short)(u >> 16);
}
__device__ __forceinline__ float b2f(unsigned short u) {
    union { unsigned u; float f; } c; c.u = ((unsigned)u) << 16;
    return c.f;
}

// ---------------- K0: ALL prepasses (block-range dispatch) ----------------
// blk [0,448):      Wall hi/lo + bias448
// blk [448,1600):   Wb conv-weight pack
// blk [1600,1860):  msP halo zero
// blk [1860,5956):  msP interior (ms -> padded bf16 hi, transposed)
__global__ __launch_bounds__(256) void k0(
    const float* __restrict__ Wc_w, const float* __restrict__ Wc_b,
    const float* __restrict__ Wf_w, const float* __restrict__ Wf_b,
    const float* __restrict__ Wk_w, const float* __restrict__ Wk_b,
    const float* __restrict__ Wv, const float* __restrict__ ms,
    unsigned short* __restrict__ Wall, unsigned short* __restrict__ Wallo,
    float* __restrict__ bias448, unsigned short* __restrict__ Wb,
    unsigned short* __restrict__ msP) {
    __shared__ float Ls[32][65];
    int blk = blockIdx.x;
    int t = threadIdx.x;
    if (blk < 448) {
        int o = blk * 256 + t;                    // 114688
        int ci8 = o & 7;
        int idx = o >> 3;                         // sc4*448 + row
        int row = idx % 448;
        int sc4 = idx / 448;                      // s*4 + c4
        int f = (sc4 >> 2) * 32 + (sc4 & 3) * 8 + ci8;
        float w;
        if (row < 128) {
            float s = 0.f;
            for (int o2 = 0; o2 < 128; ++o2) s += Wc_w[o2 * 128 + row] * Wf_w[o2 * 256 + f];
            w = s;
        } else if (row < 384) {
            int p = (row - 128) >> 1;
            w = (row & 1) ? Wk_w[p * 256 + f] : Wf_w[p * 256 + f];
        } else if (row == 384) {
            float s = 0.f;
            for (int o2 = 0; o2 < 128; ++o2) s += Wc_b[o2] * Wf_w[o2 * 256 + f];
            w = s;
        } else w = 0.f;
        unsigned short hi = f2b(w);
        Wall[o] = hi;
        Wallo[o] = f2b(w - b2f(hi));
        if (o < 448) {
            float bb;
            if (o < 128) {
                float s = 0.f;
                for (int o2 = 0; o2 < 128; ++o2) s += Wc_w[o2 * 128 + o] * Wf_b[o2];
                bb = s;
            } else if (o < 384) {
                int p = (o - 128) >> 1;
                bb = (o & 1) ? Wk_b[p] : Wf_b[p];
            } else if (o == 384) {
                float s = 0.f;
                for (int o2 = 0; o2 < 128; ++o2) s += Wc_b[o2] * Wf_b[o2];
                bb = s;
            } else if (o == 385) bb = -1.f;
            else bb = 0.f;
            bias448[o] = bb;
        }
    } else if (blk < 1600) {
        int o = (blk - 448) * 256 + t;            // 294912
        int ci8 = o & 7;
        int co  = (o >> 3) & 127;
        int c4  = (o >> 10) & 3;
        int s   = (o >> 12) & 7;
        int khw = o >> 15;                        // [0,9)
        int ci  = s * 32 + c4 * 8 + ci8;
        int kh  = khw / 3, kw = khw - kh * 3;
        Wb[o] = f2b(Wv[((co * 256 + ci) * 3 + kh) * 3 + kw]);
    } else if (blk < 1860) {
        int i = (blk - 1600) * 256 + t;           // 66560 exactly
        if (i < 66560) {
            size_t off;
            if (i < 33792) {          // rows y=0,65
                int x = i % 66; int r = i / 66;
                int g = r & 31, rowi = (r >> 5) & 1, b = r >> 6;
                off = ((((size_t)b * 66 + rowi * 65) * 32) + g) * 66 + x;
            } else {                  // cols x=0,65 for y=1..64
                int k = i - 33792;
                int xi = k & 1; int g = (k >> 1) & 31; int y1 = (k >> 6) & 63; int b = k >> 12;
                off = ((((size_t)b * 66 + (y1 + 1)) * 32) + g) * 66 + xi * 65;
            }
            *(u16x8*)&msP[off * 8] = (u16x8){0, 0, 0, 0, 0, 0, 0, 0};
        }
    } else {
        int local = blk - 1860;        // 4096 = 8b * 64h * 8s
        int s = local & 7;
        int h = (local >> 3) & 63;
        int b = local >> 9;
        const float* src = ms + ((size_t)b * 256 + s * 32) * HW + h * 64;
        for (int l = t; l < 2048; l += 256) {
            int ci = l >> 6, w = l & 63;
            Ls[ci][w] = src[ci * HW + w];
        }
        __syncthreads();
        int w = t & 63, gi = t >> 6;   // gi in [0,4)
        u16x8 vh;
#pragma unroll
        for (int j = 0; j < 8; ++j) vh[j] = f2b(Ls[gi * 8 + j][w]);
        size_t offH = ((((size_t)b * 66 + (h + 1)) * 32) + (s * 4 + gi)) * 66 + (w + 1);
        *(u16x8*)&msP[offH * 8] = vh;
    }
}

// ---------------- KMM: fused k1m (qt/q/mkey/lm) + k2m (3x3 conv) ----------------
// grid 1024, block 512 (8 waves):
//   blk [0,512):    k1m — b=blk>>6, h=blk&63; wm=wid>>1 (112 rows), wn=wid&1 (x-half)
//   blk [512,1024): k2m — h XCD-chunk-swizzled; wm=wid>>1 (32 co), wn=wid&1 (x-half)
// qt/vals written as bf16 (qtB/valsB).
__global__ __launch_bounds__(512, 4) void kmm(
    const float* __restrict__ ms, const unsigned short* __restrict__ msP,
    const unsigned short* __restrict__ Wall, const unsigned short* __restrict__ Wallo,
    const float* __restrict__ bias448, const unsigned short* __restrict__ Wb,
    const float* __restrict__ Wv_b,
    unsigned short* __restrict__ qtB, float* __restrict__ lm,
    unsigned short* __restrict__ valsB) {
    __shared__ unsigned char smem[25856] __attribute__((aligned(16)));
    int t = threadIdx.x;
    int lane = t & 63, wid = t >> 6;
    int c4l = lane >> 4, lrow = lane & 15;
    int blk = blockIdx.x;

    if (blk < 512) {
        // ================= k1m part =================
        auto Bs = (unsigned short (*)[2][4][64][8])smem;   // [buf][plane][c4][x][ci8]
        float* biasS = (float*)(smem + 16384);
        float* lmAcc = (float*)(smem + 16384 + 1792);
        int wm = wid >> 1, wn = wid & 1;
        int b = blk >> 6, h = blk & 63;
        int xs = t & 63, g4 = t >> 6;              // stage role: x, 4-ci group
        int c4w = g4 >> 1, sub = g4 & 1;
        const float* msb = ms + ((size_t)b * 256 + g4 * 4) * HW + h * 64 + xs;
        for (int i = t; i < 448; i += 512) biasS[i] = bias448[i];
        if (t < 64) lmAcc[t] = 0.f;

        f32x4 acc[7][2];
#pragma unroll
        for (int mf = 0; mf < 7; ++mf)
#pragma unroll
            for (int nf = 0; nf < 2; ++nf) acc[mf][nf] = (f32x4){0.f, 0.f, 0.f, 0.f};

        const bf16x8* Whip = (const bf16x8*)Wall;
        const bf16x8* Wlop = (const bf16x8*)Wallo;

#define CVT_WRITE(bufv, F0, F1, F2, F3) do {                                    \
        unsigned short h0 = f2b(F0), h1 = f2b(F1), h2 = f2b(F2), h3 = f2b(F3);  \
        unsigned short q0 = f2b((F0) - b2f(h0)), q1 = f2b((F1) - b2f(h1));      \
        unsigned short q2 = f2b((F2) - b2f(h2)), q3 = f2b((F3) - b2f(h3));      \
        uint2 hw, lw;                                                           \
        hw.x = (unsigned)h0 | ((unsigned)h1 << 16);                             \
        hw.y = (unsigned)h2 | ((unsigned)h3 << 16);                             \
        lw.x = (unsigned)q0 | ((unsigned)q1 << 16);                             \
        lw.y = (unsigned)q2 | ((unsigned)q3 << 16);                             \
        *(uint2*)&Bs[bufv][0][c4w][xs][sub * 4] = hw;                           \
        *(uint2*)&Bs[bufv][1][c4w][xs][sub * 4] = lw;                           \
    } while (0)

        {   // prologue: stage s=0 into buf0
            float f0 = msb[0], f1 = msb[HW], f2 = msb[2 * HW], f3 = msb[3 * HW];
            CVT_WRITE(0, f0, f1, f2, f3);
        }
        __syncthreads();

        for (int s = 0; s < 8; ++s) {
            int cur = s & 1;
            float fn0, fn1, fn2, fn3;
            if (s < 7) {   // issue next-step loads early (latency hides under MFMA)
                const float* p = msb + (size_t)(s + 1) * 32 * HW;
                fn0 = p[0]; fn1 = p[HW]; fn2 = p[2 * HW]; fn3 = p[3 * HW];
            }
            bf16x8 bh[2], bl[2];
#pragma unroll
            for (int nf = 0; nf < 2; ++nf) {
                int x = wn * 32 + nf * 16 + lrow;
                bh[nf] = *(const bf16x8*)&Bs[cur][0][c4l][x][0];
                bl[nf] = *(const bf16x8*)&Bs[cur][1][c4l][x][0];
            }
#pragma unroll
            for (int mf = 0; mf < 7; ++mf) {
                size_t widx = (size_t)(s * 4 + c4l) * 448 + wm * 112 + mf * 16 + lrow;
                bf16x8 ah = Whip[widx];
                bf16x8 al = Wlop[widx];
#pragma unroll
                for (int nf = 0; nf < 2; ++nf) {
                    acc[mf][nf] = __builtin_amdgcn_mfma_f32_16x16x32_bf16(ah, bh[nf], acc[mf][nf], 0, 0, 0);
                    acc[mf][nf] = __builtin_amdgcn_mfma_f32_16x16x32_bf16(ah, bl[nf], acc[mf][nf], 0, 0, 0);
                    acc[mf][nf] = __builtin_amdgcn_mfma_f32_16x16x32_bf16(al, bh[nf], acc[mf][nf], 0, 0, 0);
                }
            }
            if (s < 7) CVT_WRITE(cur ^ 1, fn0, fn1, fn2, fn3);
            __syncthreads();
        }
#undef CVT_WRITE

        // epilogue: D layout col=lane&15 (px), row=(lane>>4)*4+j
        int px0 = wn * 32;
        float lmp[2] = {0.f, 0.f};
#pragma unroll
        for (int mf = 0; mf < 7; ++mf) {
            int base = wm * 112 + mf * 16;
            int r0 = base + c4l * 4;
            if (base < 128) {
#pragma unroll
                for (int nf = 0; nf < 2; ++nf) {
                    int x = px0 + nf * 16 + lrow;
                    unsigned short* dst = qtB + ((size_t)b * 128 + r0) * HW + h * 64 + x;
                    f32x4 v = acc[mf][nf];
#pragma unroll
                    for (int j = 0; j < 4; ++j)
                        dst[(size_t)j * HW] = f2b(v[j] + biasS[r0 + j]);
                }
            } else {
                float b0 = biasS[r0], b1 = biasS[r0 + 1], b2 = biasS[r0 + 2], b3 = biasS[r0 + 3];
#pragma unroll
                for (int nf = 0; nf < 2; ++nf) {
                    f32x4 v = acc[mf][nf];
                    lmp[nf] += (v[0] + b0) * (v[1] + b1) + (v[2] + b2) * (v[3] + b3);
                }
            }
        }
        if (wm != 0) {
#pragma unroll
            for (int nf = 0; nf < 2; ++nf) {
                lmp[nf] += __shfl_xor(lmp[nf], 16);
                lmp[nf] += __shfl_xor(lmp[nf], 32);
            }
            if (c4l == 0) {
#pragma unroll
                for (int nf = 0; nf < 2; ++nf)
                    atomicAdd(&lmAcc[px0 + nf * 16 + lrow], lmp[nf]);
            }
        }
        __syncthreads();
        if (t < 64) lm[b * HW + h * 64 + t] = lmAcc[t];
    } else {
        // ================= k2m part =================
        auto Bs = (unsigned short (*)[6336])smem;          // [buf][792 chunks * 8]
        float* biasS = (float*)(smem + 25344);
        int local = blk - 512;
        int b = local >> 6;
        int hl = local & 63;
        int h = ((hl & 7) << 3) | (hl >> 3);   // XCD h-chunking (bijective 3-bit swap)
        int wm = wid >> 1, wn = wid & 1;
        if (t < 128) biasS[t] = Wv_b[t];

        f32x4 acc[2][2];
#pragma unroll
        for (int mf = 0; mf < 2; ++mf)
#pragma unroll
            for (int nf = 0; nf < 2; ++nf) acc[mf][nf] = (f32x4){0.f, 0.f, 0.f, 0.f};

        const bf16x8* Wbp = (const bf16x8*)Wb;

#define STAGE2(bufv, sv) do {                                                       \
        for (int iter = 0; iter < 2; ++iter) {                                      \
            int q0 = iter * 512 + (wid << 6);                                       \
            int q = q0 + lane;                                                      \
            if (q < 792) {                                                          \
                int rc = q / 66; int x = q - rc * 66;                               \
                int r = rc >> 2, c4 = rc & 3;                                       \
                int y = h + r;                      /* msP rows h-1..h+1 */         \
                const unsigned short* gp = msP +                                    \
                    (((((size_t)b * 66 + y) * 32) + ((sv) * 4 + c4)) * 66 + x) * 8; \
                unsigned short* lp = &Bs[bufv][q0 * 8];                             \
                __builtin_amdgcn_global_load_lds(                                   \
                    (const __attribute__((address_space(1))) void*)gp,              \
                    (__attribute__((address_space(3))) void*)lp, 16, 0, 0);         \
            }                                                                       \
        }                                                                           \
    } while (0)

        STAGE2(0, 0);
        __syncthreads();

        for (int s = 0; s < 8; ++s) {
            int cur = s & 1;
            if (s < 7) STAGE2(cur ^ 1, s + 1);
#pragma unroll
            for (int khw = 0; khw < 9; ++khw) {
                int kh = khw / 3, kw = khw - 3 * (khw / 3);
                bf16x8 a[2];
#pragma unroll
                for (int mf = 0; mf < 2; ++mf)
                    a[mf] = Wbp[((khw * 8 + s) * 4 + c4l) * 128 + wm * 32 + mf * 16 + lrow];
                bf16x8 bf[2];
#pragma unroll
                for (int nf = 0; nf < 2; ++nf) {
                    int chunk = (kh * 4 + c4l) * 66 + wn * 32 + nf * 16 + lrow + kw;
                    bf[nf] = *(const bf16x8*)&Bs[cur][chunk * 8];
                }
#pragma unroll
                for (int mf = 0; mf < 2; ++mf)
#pragma unroll
                    for (int nf = 0; nf < 2; ++nf)
                        acc[mf][nf] = __builtin_amdgcn_mfma_f32_16x16x32_bf16(
                            a[mf], bf[nf], acc[mf][nf], 0, 0, 0);
            }
            __syncthreads();
        }
#undef STAGE2

        // epilogue: D layout col=lane&15 (px), row=(lane>>4)*4+j (co)
#pragma unroll
        for (int mf = 0; mf < 2; ++mf) {
            int co0 = wm * 32 + mf * 16 + c4l * 4;
#pragma unroll
            for (int nf = 0; nf < 2; ++nf) {
                int x = wn * 32 + nf * 16 + lrow;
                unsigned short* dst = valsB + (((size_t)b * 128 + co0) * HW) + h * 64 + x;
                f32x4 v = acc[mf][nf];
#pragma unroll
                for (int j = 0; j < 4; ++j)
                    dst[(size_t)j * HW] = f2b(v[j] + biasS[co0 + j]);
            }
        }
    }
}

// ---------------- K3: register-diet logits -> softmax -> combine ----------------
// grid 2048 (XCD chunk-swizzled); block 256: xg = t&15 (4x each), cq = t>>4 (8c each).
// (256,4): VGPR cap 128. Peak liveness ~125 (cx 96 + packed qvp 8 + misc) — fits.
// qv stays PACKED (8 u32, unpacked per-use) to stay under the cap (r7 lesson).
__global__ __launch_bounds__(256, 4) void k3(
    const float* __restrict__ ctx, const unsigned short* __restrict__ qtB,
    const unsigned short* __restrict__ valsB, const float* __restrict__ lm,
    float* __restrict__ out) {
    __shared__ float part[4][3][64];
    __shared__ float attnS[4][64];
    int t = threadIdx.x;
    int lane = t & 63, wv = t >> 6;
    int xg = t & 15, cq = t >> 4;
    int blk0 = blockIdx.x;
    int blk = (blk0 & 7) * 256 + (blk0 >> 3);   // bijective XCD chunk swizzle (2048 = 8*256)
    int b = blk >> 8, y = (blk >> 1) & 127, xh = blk & 1;
    int h = y >> 1;
    int x0 = xh * 64 + xg * 4;
    int p0 = xh * 32 + xg * 2;

    // qv: keep packed (8 regs, not 16)
    const unsigned short* qb = qtB + ((size_t)b * 128 + cq * 8) * HW + h * 64 + p0;
    unsigned qvp[8];
#pragma unroll
    for (int j = 0; j < 8; ++j) qvp[j] = *(const unsigned*)&qb[(size_t)j * HW];

    float4 cx[3][8];
#pragma unroll
    for (int n = 0; n < 3; ++n) {
        const float* cb = ctx + ((size_t)(n * 8 + b) * 128 + cq * 8) * YX + (size_t)y * 128 + x0;
#pragma unroll
        for (int j = 0; j < 8; ++j) cx[n][j] = *(const float4*)&cb[(size_t)j * YX];
    }
    // per-n logit partials; unpack qv on the fly
#pragma unroll
    for (int n = 0; n < 3; ++n) {
        float lp[4] = {0.f, 0.f, 0.f, 0.f};
#pragma unroll
        for (int j = 0; j < 8; ++j) {
            float qx = b2f((unsigned short)(qvp[j] & 0xffffu));
            float qy = b2f((unsigned short)(qvp[j] >> 16));
            lp[0] += cx[n][j].x * qx;
            lp[1] += cx[n][j].y * qx;
            lp[2] += cx[n][j].z * qy;
            lp[3] += cx[n][j].w * qy;
        }
#pragma unroll
        for (int xl = 0; xl < 4; ++xl) {
            float v = lp[xl];
            v += __shfl_xor(v, 16);
            v += __shfl_xor(v, 32);
            lp[xl] = v;
        }
        if (lane < 16) {
#pragma unroll
            for (int xl = 0; xl < 4; ++xl)
                part[wv][n][lane * 4 + xl] = lp[xl];
        }
    }
    __syncthreads();
    if (t < 64) {
        float l0 = part[0][0][t] + part[1][0][t] + part[2][0][t] + part[3][0][t];
        float l1 = part[0][1][t] + part[1][1][t] + part[2][1][t] + part[3][1][t];
        float l2 = part[0][2][t] + part[1][2][t] + part[2][2][t] + part[3][2][t];
        float l3 = lm[(size_t)b * HW + h * 64 + xh * 32 + (t >> 1)];
        float m = fmaxf(fmaxf(l0, l1), fmaxf(l2, l3));
        float e0 = __expf(l0 - m), e1 = __expf(l1 - m), e2 = __expf(l2 - m), e3 = __expf(l3 - m);
        float inv = 1.f / (e0 + e1 + e2 + e3);
        attnS[0][t] = e0 * inv; attnS[1][t] = e1 * inv;
        attnS[2][t] = e2 * inv; attnS[3][t] = e3 * inv;
    }
    __syncthreads();
    // vv: load packed only now (reuses qvp's register space once qv is dead)
    const unsigned short* vb = valsB + ((size_t)b * 128 + cq * 8) * HW + h * 64 + p0;
    unsigned vvp[8];
#pragma unroll
    for (int j = 0; j < 8; ++j) vvp[j] = *(const unsigned*)&vb[(size_t)j * HW];
    float a0[4], a1[4], a2[4], a3[4];
#pragma unroll
    for (int xl = 0; xl < 4; ++xl) {
        a0[xl] = attnS[0][xg * 4 + xl];
        a1[xl] = attnS[1][xg * 4 + xl];
        a2[xl] = attnS[2][xg * 4 + xl];
        a3[xl] = attnS[3][xg * 4 + xl];
    }
    float* obase = out + ((size_t)b * 128 + cq * 8) * YX + (size_t)y * 128 + x0;
#pragma unroll
    for (int j = 0; j < 8; ++j) {
        float vx = b2f((unsigned short)(vvp[j] & 0xffffu));
        float vy = b2f((unsigned short)(vvp[j] >> 16));
        float4 o;
        o.x = a3[0] * vx + a0[0] * cx[0][j].x + a1[0] * cx[1][j].x + a2[0] * cx[2][j].x;
        o.y = a3[1] * vx + a0[1] * cx[0][j].y + a1[1] * cx[1][j].y + a2[1] * cx[2][j].y;
        o.z = a3[2] * vy + a0[2] * cx[0][j].z + a1[2] * cx[1][j].z + a2[2] * cx[2][j].z;
        o.w = a3[3] * vy + a0[3] * cx[0][j].w + a1[3] * cx[1][j].w + a2[3] * cx[2][j].w;
        *(float4*)&obase[(size_t)j * YX] = o;
    }
}

extern "C" void kernel_launch(void* const* d_in, const int* in_sizes, int n_in,
                              void* d_out, int out_size, void* d_ws, size_t ws_size,
                              hipStream_t stream) {
    const float* ctx  = (const float*)d_in[0];
    const float* ms   = (const float*)d_in[1];
    const float* Wc_w = (const float*)d_in[2];
    const float* Wc_b = (const float*)d_in[3];
    const float* Wf_w = (const float*)d_in[4];
    const float* Wf_b = (const float*)d_in[5];
    const float* Wk_w = (const float*)d_in[6];
    const float* Wk_b = (const float*)d_in[7];
    const float* Wv_w = (const float*)d_in[8];
    const float* Wv_b = (const float*)d_in[9];
    float* out = (float*)d_out;
    float* ws = (float*)d_ws;
    float* bias448 = ws + WS_BIAS;
    float* lmp     = ws + WS_LM;
    unsigned short* qtBp   = (unsigned short*)(ws + WS_QT);
    unsigned short* valsBp = (unsigned short*)(ws + WS_VALS);
    unsigned short* Wallp  = (unsigned short*)(ws + WS_WALL);
    unsigned short* Wallop = (unsigned short*)(ws + WS_WALLO);
    unsigned short* msPp   = (unsigned short*)(ws + WS_MSP);
    unsigned short* Wbp    = (unsigned short*)(ws + WS_WB);

    hipLaunchKernelGGL(k0, dim3(5956), dim3(256), 0, stream, Wc_w, Wc_b, Wf_w, Wf_b,
                       Wk_w, Wk_b, Wv_w, ms, Wallp, Wallop, bias448, Wbp, msPp);
    hipLaunchKernelGGL(kmm, dim3(1024), dim3(512), 0, stream, ms, msPp, Wallp, Wallop,
                       bias448, Wbp, Wv_b, qtBp, lmp, valsBp);
    hipLaunchKernelGGL(k3, dim3(2048), dim3(256), 0, stream, ctx, qtBp, valsBp, lmp, out);
}

// Round 10
// 143.824 us; speedup vs baseline: 1.0977x; 1.0977x over previous
//
#include <hip/hip_runtime.h>

#define NCTX 3
#define B 8
#define CC 128
#define CF 256
#define H 64
#define W 64
#define HW 4096
#define YX 16384   // (2H)*(2W)

// workspace layout (float offsets)
#define WS_QT    0          // bf16 qtB: B*CC*HW ushorts
#define WS_VALS  4194304    // bf16 valsB: B*CC*HW ushorts
#define WS_BIAS  8388608    // bias448 (448 floats)
#define WS_LM    8421376    // B*HW
#define WS_WALL  8454144    // bf16 Wall hi: 8*4*448*8 = 114688 ushorts
#define WS_MSP   8552960    // bf16 msP hi: 8*66*32*66*8 = 8921088 ushorts
#define WS_WB    13013504   // bf16 Wb: 9*8*4*128*8 = 294912 ushorts
#define WS_WALLO 13160960   // bf16 Wall lo: 114688 ushorts (end 13218304)

typedef __attribute__((ext_vector_type(8))) short bf16x8;
typedef __attribute__((ext_vector_type(4))) float f32x4;
typedef __attribute__((ext_vector_type(8))) unsigned short u16x8;

__device__ __forceinline__ unsigned short f2b(float f) {
    union { float f; unsigned u; } c; c.f = f;
    unsigned u = c.u + 0x7FFFu + ((c.u >> 16) & 1u);
    return (unsigned short)(u >> 16);
}
__device__ __forceinline__ float b2f(unsigned short u) {
    union { unsigned u; float f; } c; c.u = ((unsigned)u) << 16;
    return c.f;
}

// ---------------- K0: ALL prepasses (block-range dispatch) ----------------
// blk [0,448):      Wall hi/lo + bias448
// blk [448,1600):   Wb conv-weight pack
// blk [1600,1860):  msP halo zero
// blk [1860,5956):  msP interior (ms -> padded bf16 hi, transposed)
__global__ __launch_bounds__(256) void k0(
    const float* __restrict__ Wc_w, const float* __restrict__ Wc_b,
    const float* __restrict__ Wf_w, const float* __restrict__ Wf_b,
    const float* __restrict__ Wk_w, const float* __restrict__ Wk_b,
    const float* __restrict__ Wv, const float* __restrict__ ms,
    unsigned short* __restrict__ Wall, unsigned short* __restrict__ Wallo,
    float* __restrict__ bias448, unsigned short* __restrict__ Wb,
    unsigned short* __restrict__ msP) {
    __shared__ float Ls[32][65];
    int blk = blockIdx.x;
    int t = threadIdx.x;
    if (blk < 448) {
        int o = blk * 256 + t;                    // 114688
        int ci8 = o & 7;
        int idx = o >> 3;                         // sc4*448 + row
        int row = idx % 448;
        int sc4 = idx / 448;                      // s*4 + c4
        int f = (sc4 >> 2) * 32 + (sc4 & 3) * 8 + ci8;
        float w;
        if (row < 128) {
            float s = 0.f;
            for (int o2 = 0; o2 < 128; ++o2) s += Wc_w[o2 * 128 + row] * Wf_w[o2 * 256 + f];
            w = s;
        } else if (row < 384) {
            int p = (row - 128) >> 1;
            w = (row & 1) ? Wk_w[p * 256 + f] : Wf_w[p * 256 + f];
        } else if (row == 384) {
            float s = 0.f;
            for (int o2 = 0; o2 < 128; ++o2) s += Wc_b[o2] * Wf_w[o2 * 256 + f];
            w = s;
        } else w = 0.f;
        unsigned short hi = f2b(w);
        Wall[o] = hi;
        Wallo[o] = f2b(w - b2f(hi));
        if (o < 448) {
            float bb;
            if (o < 128) {
                float s = 0.f;
                for (int o2 = 0; o2 < 128; ++o2) s += Wc_w[o2 * 128 + o] * Wf_b[o2];
                bb = s;
            } else if (o < 384) {
                int p = (o - 128) >> 1;
                bb = (o & 1) ? Wk_b[p] : Wf_b[p];
            } else if (o == 384) {
                float s = 0.f;
                for (int o2 = 0; o2 < 128; ++o2) s += Wc_b[o2] * Wf_b[o2];
                bb = s;
            } else if (o == 385) bb = -1.f;
            else bb = 0.f;
            bias448[o] = bb;
        }
    } else if (blk < 1600) {
        int o = (blk - 448) * 256 + t;            // 294912
        int ci8 = o & 7;
        int co  = (o >> 3) & 127;
        int c4  = (o >> 10) & 3;
        int s   = (o >> 12) & 7;
        int khw = o >> 15;                        // [0,9)
        int ci  = s * 32 + c4 * 8 + ci8;
        int kh  = khw / 3, kw = khw - kh * 3;
        Wb[o] = f2b(Wv[((co * 256 + ci) * 3 + kh) * 3 + kw]);
    } else if (blk < 1860) {
        int i = (blk - 1600) * 256 + t;           // 66560 exactly
        if (i < 66560) {
            size_t off;
            if (i < 33792) {          // rows y=0,65
                int x = i % 66; int r = i / 66;
                int g = r & 31, rowi = (r >> 5) & 1, b = r >> 6;
                off = ((((size_t)b * 66 + rowi * 65) * 32) + g) * 66 + x;
            } else {                  // cols x=0,65 for y=1..64
                int k = i - 33792;
                int xi = k & 1; int g = (k >> 1) & 31; int y1 = (k >> 6) & 63; int b = k >> 12;
                off = ((((size_t)b * 66 + (y1 + 1)) * 32) + g) * 66 + xi * 65;
            }
            *(u16x8*)&msP[off * 8] = (u16x8){0, 0, 0, 0, 0, 0, 0, 0};
        }
    } else {
        int local = blk - 1860;        // 4096 = 8b * 64h * 8s
        int s = local & 7;
        int h = (local >> 3) & 63;
        int b = local >> 9;
        const float* src = ms + ((size_t)b * 256 + s * 32) * HW + h * 64;
        for (int l = t; l < 2048; l += 256) {
            int ci = l >> 6, w = l & 63;
            Ls[ci][w] = src[ci * HW + w];
        }
        __syncthreads();
        int w = t & 63, gi = t >> 6;   // gi in [0,4)
        u16x8 vh;
#pragma unroll
        for (int j = 0; j < 8; ++j) vh[j] = f2b(Ls[gi * 8 + j][w]);
        size_t offH = ((((size_t)b * 66 + (h + 1)) * 32) + (s * 4 + gi)) * 66 + (w + 1);
        *(u16x8*)&msP[offH * 8] = vh;
    }
}

// ---------------- KMM: fused k1m (qt/q/mkey/lm) + k2m (3x3 conv) ----------------
// grid 1024, block 512 (8 waves):
//   blk [0,512):    k1m — b=blk>>6, h=blk&63; wm=wid>>1 (112 rows), wn=wid&1 (x-half)
//   blk [512,1024): k2m — h XCD-chunk-swizzled; wm=wid>>1 (32 co), wn=wid&1 (x-half)
// qt/vals written as bf16 (qtB/valsB).
__global__ __launch_bounds__(512, 4) void kmm(
    const float* __restrict__ ms, const unsigned short* __restrict__ msP,
    const unsigned short* __restrict__ Wall, const unsigned short* __restrict__ Wallo,
    const float* __restrict__ bias448, const unsigned short* __restrict__ Wb,
    const float* __restrict__ Wv_b,
    unsigned short* __restrict__ qtB, float* __restrict__ lm,
    unsigned short* __restrict__ valsB) {
    __shared__ unsigned char smem[25856] __attribute__((aligned(16)));
    int t = threadIdx.x;
    int lane = t & 63, wid = t >> 6;
    int c4l = lane >> 4, lrow = lane & 15;
    int blk = blockIdx.x;

    if (blk < 512) {
        // ================= k1m part =================
        auto Bs = (unsigned short (*)[2][4][64][8])smem;   // [buf][plane][c4][x][ci8]
        float* biasS = (float*)(smem + 16384);
        float* lmAcc = (float*)(smem + 16384 + 1792);
        int wm = wid >> 1, wn = wid & 1;
        int b = blk >> 6, h = blk & 63;
        int xs = t & 63, g4 = t >> 6;              // stage role: x, 4-ci group
        int c4w = g4 >> 1, sub = g4 & 1;
        const float* msb = ms + ((size_t)b * 256 + g4 * 4) * HW + h * 64 + xs;
        for (int i = t; i < 448; i += 512) biasS[i] = bias448[i];
        if (t < 64) lmAcc[t] = 0.f;

        f32x4 acc[7][2];
#pragma unroll
        for (int mf = 0; mf < 7; ++mf)
#pragma unroll
            for (int nf = 0; nf < 2; ++nf) acc[mf][nf] = (f32x4){0.f, 0.f, 0.f, 0.f};

        const bf16x8* Whip = (const bf16x8*)Wall;
        const bf16x8* Wlop = (const bf16x8*)Wallo;

#define CVT_WRITE(bufv, F0, F1, F2, F3) do {                                    \
        unsigned short h0 = f2b(F0), h1 = f2b(F1), h2 = f2b(F2), h3 = f2b(F3);  \
        unsigned short q0 = f2b((F0) - b2f(h0)), q1 = f2b((F1) - b2f(h1));      \
        unsigned short q2 = f2b((F2) - b2f(h2)), q3 = f2b((F3) - b2f(h3));      \
        uint2 hw, lw;                                                           \
        hw.x = (unsigned)h0 | ((unsigned)h1 << 16);                             \
        hw.y = (unsigned)h2 | ((unsigned)h3 << 16);                             \
        lw.x = (unsigned)q0 | ((unsigned)q1 << 16);                             \
        lw.y = (unsigned)q2 | ((unsigned)q3 << 16);                             \
        *(uint2*)&Bs[bufv][0][c4w][xs][sub * 4] = hw;                           \
        *(uint2*)&Bs[bufv][1][c4w][xs][sub * 4] = lw;                           \
    } while (0)

        {   // prologue: stage s=0 into buf0
            float f0 = msb[0], f1 = msb[HW], f2 = msb[2 * HW], f3 = msb[3 * HW];
            CVT_WRITE(0, f0, f1, f2, f3);
        }
        __syncthreads();

        for (int s = 0; s < 8; ++s) {
            int cur = s & 1;
            float fn0, fn1, fn2, fn3;
            if (s < 7) {   // issue next-step loads early (latency hides under MFMA)
                const float* p = msb + (size_t)(s + 1) * 32 * HW;
                fn0 = p[0]; fn1 = p[HW]; fn2 = p[2 * HW]; fn3 = p[3 * HW];
            }
            bf16x8 bh[2], bl[2];
#pragma unroll
            for (int nf = 0; nf < 2; ++nf) {
                int x = wn * 32 + nf * 16 + lrow;
                bh[nf] = *(const bf16x8*)&Bs[cur][0][c4l][x][0];
                bl[nf] = *(const bf16x8*)&Bs[cur][1][c4l][x][0];
            }
#pragma unroll
            for (int mf = 0; mf < 7; ++mf) {
                size_t widx = (size_t)(s * 4 + c4l) * 448 + wm * 112 + mf * 16 + lrow;
                bf16x8 ah = Whip[widx];
                bf16x8 al = Wlop[widx];
#pragma unroll
                for (int nf = 0; nf < 2; ++nf) {
                    acc[mf][nf] = __builtin_amdgcn_mfma_f32_16x16x32_bf16(ah, bh[nf], acc[mf][nf], 0, 0, 0);
                    acc[mf][nf] = __builtin_amdgcn_mfma_f32_16x16x32_bf16(ah, bl[nf], acc[mf][nf], 0, 0, 0);
                    acc[mf][nf] = __builtin_amdgcn_mfma_f32_16x16x32_bf16(al, bh[nf], acc[mf][nf], 0, 0, 0);
                }
            }
            if (s < 7) CVT_WRITE(cur ^ 1, fn0, fn1, fn2, fn3);
            __syncthreads();
        }
#undef CVT_WRITE

        // epilogue: D layout col=lane&15 (px), row=(lane>>4)*4+j
        int px0 = wn * 32;
        float lmp[2] = {0.f, 0.f};
#pragma unroll
        for (int mf = 0; mf < 7; ++mf) {
            int base = wm * 112 + mf * 16;
            int r0 = base + c4l * 4;
            if (base < 128) {
#pragma unroll
                for (int nf = 0; nf < 2; ++nf) {
                    int x = px0 + nf * 16 + lrow;
                    unsigned short* dst = qtB + ((size_t)b * 128 + r0) * HW + h * 64 + x;
                    f32x4 v = acc[mf][nf];
#pragma unroll
                    for (int j = 0; j < 4; ++j)
                        dst[(size_t)j * HW] = f2b(v[j] + biasS[r0 + j]);
                }
            } else {
                float b0 = biasS[r0], b1 = biasS[r0 + 1], b2 = biasS[r0 + 2], b3 = biasS[r0 + 3];
#pragma unroll
                for (int nf = 0; nf < 2; ++nf) {
                    f32x4 v = acc[mf][nf];
                    lmp[nf] += (v[0] + b0) * (v[1] + b1) + (v[2] + b2) * (v[3] + b3);
                }
            }
        }
        if (wm != 0) {
#pragma unroll
            for (int nf = 0; nf < 2; ++nf) {
                lmp[nf] += __shfl_xor(lmp[nf], 16);
                lmp[nf] += __shfl_xor(lmp[nf], 32);
            }
            if (c4l == 0) {
#pragma unroll
                for (int nf = 0; nf < 2; ++nf)
                    atomicAdd(&lmAcc[px0 + nf * 16 + lrow], lmp[nf]);
            }
        }
        __syncthreads();
        if (t < 64) lm[b * HW + h * 64 + t] = lmAcc[t];
    } else {
        // ================= k2m part =================
        auto Bs = (unsigned short (*)[6336])smem;          // [buf][792 chunks * 8]
        float* biasS = (float*)(smem + 25344);
        int local = blk - 512;
        int b = local >> 6;
        int hl = local & 63;
        int h = ((hl & 7) << 3) | (hl >> 3);   // XCD h-chunking (bijective 3-bit swap)
        int wm = wid >> 1, wn = wid & 1;
        if (t < 128) biasS[t] = Wv_b[t];

        f32x4 acc[2][2];
#pragma unroll
        for (int mf = 0; mf < 2; ++mf)
#pragma unroll
            for (int nf = 0; nf < 2; ++nf) acc[mf][nf] = (f32x4){0.f, 0.f, 0.f, 0.f};

        const bf16x8* Wbp = (const bf16x8*)Wb;

#define STAGE2(bufv, sv) do {                                                       \
        for (int iter = 0; iter < 2; ++iter) {                                      \
            int q0 = iter * 512 + (wid << 6);                                       \
            int q = q0 + lane;                                                      \
            if (q < 792) {                                                          \
                int rc = q / 66; int x = q - rc * 66;                               \
                int r = rc >> 2, c4 = rc & 3;                                       \
                int y = h + r;                      /* msP rows h-1..h+1 */         \
                const unsigned short* gp = msP +                                    \
                    (((((size_t)b * 66 + y) * 32) + ((sv) * 4 + c4)) * 66 + x) * 8; \
                unsigned short* lp = &Bs[bufv][q0 * 8];                             \
                __builtin_amdgcn_global_load_lds(                                   \
                    (const __attribute__((address_space(1))) void*)gp,              \
                    (__attribute__((address_space(3))) void*)lp, 16, 0, 0);         \
            }                                                                       \
        }                                                                           \
    } while (0)

        STAGE2(0, 0);
        __syncthreads();

        for (int s = 0; s < 8; ++s) {
            int cur = s & 1;
            if (s < 7) STAGE2(cur ^ 1, s + 1);
#pragma unroll
            for (int khw = 0; khw < 9; ++khw) {
                int kh = khw / 3, kw = khw - 3 * (khw / 3);
                bf16x8 a[2];
#pragma unroll
                for (int mf = 0; mf < 2; ++mf)
                    a[mf] = Wbp[((khw * 8 + s) * 4 + c4l) * 128 + wm * 32 + mf * 16 + lrow];
                bf16x8 bf[2];
#pragma unroll
                for (int nf = 0; nf < 2; ++nf) {
                    int chunk = (kh * 4 + c4l) * 66 + wn * 32 + nf * 16 + lrow + kw;
                    bf[nf] = *(const bf16x8*)&Bs[cur][chunk * 8];
                }
#pragma unroll
                for (int mf = 0; mf < 2; ++mf)
#pragma unroll
                    for (int nf = 0; nf < 2; ++nf)
                        acc[mf][nf] = __builtin_amdgcn_mfma_f32_16x16x32_bf16(
                            a[mf], bf[nf], acc[mf][nf], 0, 0, 0);
            }
            __syncthreads();
        }
#undef STAGE2

        // epilogue: D layout col=lane&15 (px), row=(lane>>4)*4+j (co)
#pragma unroll
        for (int mf = 0; mf < 2; ++mf) {
            int co0 = wm * 32 + mf * 16 + c4l * 4;
#pragma unroll
            for (int nf = 0; nf < 2; ++nf) {
                int x = wn * 32 + nf * 16 + lrow;
                unsigned short* dst = valsB + (((size_t)b * 128 + co0) * HW) + h * 64 + x;
                f32x4 v = acc[mf][nf];
#pragma unroll
                for (int j = 0; j < 4; ++j)
                    dst[(size_t)j * HW] = f2b(v[j] + biasS[co0 + j]);
            }
        }
    }
}

// ---------------- K3: ONLINE-softmax combine (one ctx tile live at a time) --------
// grid 2048 (XCD chunk-swizzled); block 256: xg = t&15 (4x each), cq = t>>4 (8c each).
// Peak liveness ~100 VGPR (out_acc 32 + one cx 32 + qvp 8 + m/sum 8 + misc) ->
// fits the 128 cap of (256,4) with margin (r7/r9 lesson: cx[3][8]=96 never fits).
__global__ __launch_bounds__(256, 4) void k3(
    const float* __restrict__ ctx, const unsigned short* __restrict__ qtB,
    const unsigned short* __restrict__ valsB, const float* __restrict__ lm,
    float* __restrict__ out) {
    __shared__ float part[4][64];
    __shared__ float logitS[64];
    int t = threadIdx.x;
    int lane = t & 63, wv = t >> 6;
    int xg = t & 15, cq = t >> 4;
    int blk0 = blockIdx.x;
    int blk = (blk0 & 7) * 256 + (blk0 >> 3);   // bijective XCD chunk swizzle (2048 = 8*256)
    int b = blk >> 8, y = (blk >> 1) & 127, xh = blk & 1;
    int h = y >> 1;
    int x0 = xh * 64 + xg * 4;
    int p0 = xh * 32 + xg * 2;

    // q: packed bf16 pairs (8 regs)
    const unsigned short* qb = qtB + ((size_t)b * 128 + cq * 8) * HW + h * 64 + p0;
    unsigned qvp[8];
#pragma unroll
    for (int j = 0; j < 8; ++j) qvp[j] = *(const unsigned*)&qb[(size_t)j * HW];

    // init online state from the mainline source: m = logit_main, sum = 1, acc = vals
    float lm0 = lm[(size_t)b * HW + h * 64 + p0];
    float lm1 = lm[(size_t)b * HW + h * 64 + p0 + 1];
    float m[4] = {lm0, lm0, lm1, lm1};
    float sum[4] = {1.f, 1.f, 1.f, 1.f};
    const unsigned short* vb = valsB + ((size_t)b * 128 + cq * 8) * HW + h * 64 + p0;
    float4 oa[8];
#pragma unroll
    for (int j = 0; j < 8; ++j) {
        unsigned v = *(const unsigned*)&vb[(size_t)j * HW];
        float vx = b2f((unsigned short)(v & 0xffffu));
        float vy = b2f((unsigned short)(v >> 16));
        oa[j] = (float4){vx, vx, vy, vy};
    }

#pragma unroll 1
    for (int n = 0; n < 3; ++n) {
        // load this context's tile (32 regs, released at loop end)
        const float* cb = ctx + ((size_t)(n * 8 + b) * 128 + cq * 8) * YX + (size_t)y * 128 + x0;
        float4 cx[8];
#pragma unroll
        for (int j = 0; j < 8; ++j) cx[j] = *(const float4*)&cb[(size_t)j * YX];
        // logit partials
        float lp[4] = {0.f, 0.f, 0.f, 0.f};
#pragma unroll
        for (int j = 0; j < 8; ++j) {
            float qx = b2f((unsigned short)(qvp[j] & 0xffffu));
            float qy = b2f((unsigned short)(qvp[j] >> 16));
            lp[0] += cx[j].x * qx;
            lp[1] += cx[j].y * qx;
            lp[2] += cx[j].z * qy;
            lp[3] += cx[j].w * qy;
        }
#pragma unroll
        for (int xl = 0; xl < 4; ++xl) {
            float v = lp[xl];
            v += __shfl_xor(v, 16);
            v += __shfl_xor(v, 32);
            lp[xl] = v;
        }
        if (lane < 16) {
#pragma unroll
            for (int xl = 0; xl < 4; ++xl) part[wv][lane * 4 + xl] = lp[xl];
        }
        __syncthreads();
        if (t < 64) logitS[t] = part[0][t] + part[1][t] + part[2][t] + part[3][t];
        __syncthreads();
        // online rescale + accumulate (per x position)
        float f[4], e[4];
#pragma unroll
        for (int xl = 0; xl < 4; ++xl) {
            float ln = logitS[xg * 4 + xl];
            float nm = fmaxf(m[xl], ln);
            f[xl] = __expf(m[xl] - nm);
            e[xl] = __expf(ln - nm);
            sum[xl] = sum[xl] * f[xl] + e[xl];
            m[xl] = nm;
        }
#pragma unroll
        for (int j = 0; j < 8; ++j) {
            oa[j].x = oa[j].x * f[0] + e[0] * cx[j].x;
            oa[j].y = oa[j].y * f[1] + e[1] * cx[j].y;
            oa[j].z = oa[j].z * f[2] + e[2] * cx[j].z;
            oa[j].w = oa[j].w * f[3] + e[3] * cx[j].w;
        }
    }

    // normalize + store
    float r0 = 1.f / sum[0], r1 = 1.f / sum[1], r2 = 1.f / sum[2], r3 = 1.f / sum[3];
    float* obase = out + ((size_t)b * 128 + cq * 8) * YX + (size_t)y * 128 + x0;
#pragma unroll
    for (int j = 0; j < 8; ++j) {
        float4 o;
        o.x = oa[j].x * r0;
        o.y = oa[j].y * r1;
        o.z = oa[j].z * r2;
        o.w = oa[j].w * r3;
        *(float4*)&obase[(size_t)j * YX] = o;
    }
}

extern "C" void kernel_launch(void* const* d_in, const int* in_sizes, int n_in,
                              void* d_out, int out_size, void* d_ws, size_t ws_size,
                              hipStream_t stream) {
    const float* ctx  = (const float*)d_in[0];
    const float* ms   = (const float*)d_in[1];
    const float* Wc_w = (const float*)d_in[2];
    const float* Wc_b = (const float*)d_in[3];
    const float* Wf_w = (const float*)d_in[4];
    const float* Wf_b = (const float*)d_in[5];
    const float* Wk_w = (const float*)d_in[6];
    const float* Wk_b = (const float*)d_in[7];
    const float* Wv_w = (const float*)d_in[8];
    const float* Wv_b = (const float*)d_in[9];
    float* out = (float*)d_out;
    float* ws = (float*)d_ws;
    float* bias448 = ws + WS_BIAS;
    float* lmp     = ws + WS_LM;
    unsigned short* qtBp   = (unsigned short*)(ws + WS_QT);
    unsigned short* valsBp = (unsigned short*)(ws + WS_VALS);
    unsigned short* Wallp  = (unsigned short*)(ws + WS_WALL);
    unsigned short* Wallop = (unsigned short*)(ws + WS_WALLO);
    unsigned short* msPp   = (unsigned short*)(ws + WS_MSP);
    unsigned short* Wbp    = (unsigned short*)(ws + WS_WB);

    hipLaunchKernelGGL(k0, dim3(5956), dim3(256), 0, stream, Wc_w, Wc_b, Wf_w, Wf_b,
                       Wk_w, Wk_b, Wv_w, ms, Wallp, Wallop, bias448, Wbp, msPp);
    hipLaunchKernelGGL(kmm, dim3(1024), dim3(512), 0, stream, ms, msPp, Wallp, Wallop,
                       bias448, Wbp, Wv_b, qtBp, lmp, valsBp);
    hipLaunchKernelGGL(k3, dim3(2048), dim3(256), 0, stream, ctx, qtBp, valsBp, lmp, out);
}

// Round 11
// 133.996 us; speedup vs baseline: 1.1783x; 1.0733x over previous
//
#include <hip/hip_runtime.h>

#define NCTX 3
#define B 8
#define CC 128
#define CF 256
#define H 64
#define W 64
#define HW 4096
#define YX 16384   // (2H)*(2W)

// workspace layout (float offsets)
#define WS_BIAS  8388608    // bias448 (448 floats)
#define WS_WALL  8454144    // bf16 Wall hi: 8*4*448*8 = 114688 ushorts
#define WS_MSP   8552960    // bf16 msP hi: 8*66*32*66*8 = 8921088 ushorts
#define WS_WB    13013504   // bf16 Wb: 9*8*4*128*8 = 294912 ushorts
#define WS_WALLO 13160960   // bf16 Wall lo: 114688 ushorts (end 13218304)

typedef __attribute__((ext_vector_type(8))) short bf16x8;
typedef __attribute__((ext_vector_type(4))) float f32x4;
typedef __attribute__((ext_vector_type(8))) unsigned short u16x8;

__device__ __forceinline__ unsigned short f2b(float f) {
    union { float f; unsigned u; } c; c.f = f;
    unsigned u = c.u + 0x7FFFu + ((c.u >> 16) & 1u);
    return (unsigned short)(u >> 16);
}
__device__ __forceinline__ float b2f(unsigned short u) {
    union { unsigned u; float f; } c; c.u = ((unsigned)u) << 16;
    return c.f;
}

// ---------------- K0: ALL prepasses (block-range dispatch) ----------------
__global__ __launch_bounds__(256) void k0(
    const float* __restrict__ Wc_w, const float* __restrict__ Wc_b,
    const float* __restrict__ Wf_w, const float* __restrict__ Wf_b,
    const float* __restrict__ Wk_w, const float* __restrict__ Wk_b,
    const float* __restrict__ Wv, const float* __restrict__ ms,
    unsigned short* __restrict__ Wall, unsigned short* __restrict__ Wallo,
    float* __restrict__ bias448, unsigned short* __restrict__ Wb,
    unsigned short* __restrict__ msP) {
    __shared__ float Ls[32][65];
    int blk = blockIdx.x;
    int t = threadIdx.x;
    if (blk < 448) {
        int o = blk * 256 + t;                    // 114688
        int ci8 = o & 7;
        int idx = o >> 3;                         // sc4*448 + row
        int row = idx % 448;
        int sc4 = idx / 448;                      // s*4 + c4
        int f = (sc4 >> 2) * 32 + (sc4 & 3) * 8 + ci8;
        float w;
        if (row < 128) {
            float s = 0.f;
            for (int o2 = 0; o2 < 128; ++o2) s += Wc_w[o2 * 128 + row] * Wf_w[o2 * 256 + f];
            w = s;
        } else if (row < 384) {
            int p = (row - 128) >> 1;
            w = (row & 1) ? Wk_w[p * 256 + f] : Wf_w[p * 256 + f];
        } else if (row == 384) {
            float s = 0.f;
            for (int o2 = 0; o2 < 128; ++o2) s += Wc_b[o2] * Wf_w[o2 * 256 + f];
            w = s;
        } else w = 0.f;
        unsigned short hi = f2b(w);
        Wall[o] = hi;
        Wallo[o] = f2b(w - b2f(hi));
        if (o < 448) {
            float bb;
            if (o < 128) {
                float s = 0.f;
                for (int o2 = 0; o2 < 128; ++o2) s += Wc_w[o2 * 128 + o] * Wf_b[o2];
                bb = s;
            } else if (o < 384) {
                int p = (o - 128) >> 1;
                bb = (o & 1) ? Wk_b[p] : Wf_b[p];
            } else if (o == 384) {
                float s = 0.f;
                for (int o2 = 0; o2 < 128; ++o2) s += Wc_b[o2] * Wf_b[o2];
                bb = s;
            } else if (o == 385) bb = -1.f;
            else bb = 0.f;
            bias448[o] = bb;
        }
    } else if (blk < 1600) {
        int o = (blk - 448) * 256 + t;            // 294912
        int ci8 = o & 7;
        int co  = (o >> 3) & 127;
        int c4  = (o >> 10) & 3;
        int s   = (o >> 12) & 7;
        int khw = o >> 15;                        // [0,9)
        int ci  = s * 32 + c4 * 8 + ci8;
        int kh  = khw / 3, kw = khw - kh * 3;
        Wb[o] = f2b(Wv[((co * 256 + ci) * 3 + kh) * 3 + kw]);
    } else if (blk < 1860) {
        int i = (blk - 1600) * 256 + t;           // 66560 exactly
        if (i < 66560) {
            size_t off;
            if (i < 33792) {          // rows y=0,65
                int x = i % 66; int r = i / 66;
                int g = r & 31, rowi = (r >> 5) & 1, b = r >> 6;
                off = ((((size_t)b * 66 + rowi * 65) * 32) + g) * 66 + x;
            } else {                  // cols x=0,65 for y=1..64
                int k = i - 33792;
                int xi = k & 1; int g = (k >> 1) & 31; int y1 = (k >> 6) & 63; int b = k >> 12;
                off = ((((size_t)b * 66 + (y1 + 1)) * 32) + g) * 66 + xi * 65;
            }
            *(u16x8*)&msP[off * 8] = (u16x8){0, 0, 0, 0, 0, 0, 0, 0};
        }
    } else {
        int local = blk - 1860;        // 4096 = 8b * 64h * 8s
        int s = local & 7;
        int h = (local >> 3) & 63;
        int b = local >> 9;
        const float* src = ms + ((size_t)b * 256 + s * 32) * HW + h * 64;
        for (int l = t; l < 2048; l += 256) {
            int ci = l >> 6, w = l & 63;
            Ls[ci][w] = src[ci * HW + w];
        }
        __syncthreads();
        int w = t & 63, gi = t >> 6;   // gi in [0,4)
        u16x8 vh;
#pragma unroll
        for (int j = 0; j < 8; ++j) vh[j] = f2b(Ls[gi * 8 + j][w]);
        size_t offH = ((((size_t)b * 66 + (h + 1)) * 32) + (s * 4 + gi)) * 66 + (w + 1);
        *(u16x8*)&msP[offH * 8] = vh;
    }
}

// ---------------- KFULL: fused k1m + k2m + k3, one (b,h) tile per block ----------
// grid 512 = 8b*64h, block 512 (8 waves), __launch_bounds__(512,4), LDS 63.3 KB
// Phase A: qt (bf16) + lm into LDS.  Phase B: vals (bf16) into LDS.
// Phase C: stream ctx rows y=2h,2h+1 from HBM; online softmax; write out.
// LDS map (bytes): [0:16384) qtS[128][64] bf16 | [16384:32768) vS[128][64] bf16
//  | [32768:58112) stage | [58112:59904) bias448 | [59904:60416) biasB/logitS
//  | [60416:60672) lmS | [60672:64768) part[8][128]
__global__ __launch_bounds__(512, 4) void kfull(
    const float* __restrict__ ms, const unsigned short* __restrict__ msP,
    const unsigned short* __restrict__ Wall, const unsigned short* __restrict__ Wallo,
    const float* __restrict__ bias448, const unsigned short* __restrict__ Wb,
    const float* __restrict__ Wv_b, const float* __restrict__ ctx,
    float* __restrict__ out) {
    __shared__ unsigned char smem[64768] __attribute__((aligned(16)));
    unsigned short* qtS16 = (unsigned short*)smem;
    unsigned short* vS16  = (unsigned short*)(smem + 16384);
    float* biasS = (float*)(smem + 58112);
    float* biasB = (float*)(smem + 59904);
    float* logitS = (float*)(smem + 59904);      // aliases biasB (dead by phase C)
    float* lmS   = (float*)(smem + 60416);
    float (*part)[128] = (float (*)[128])(smem + 60672);

    int t = threadIdx.x;
    int lane = t & 63, wid = t >> 6;
    int c4l = lane >> 4, lrow = lane & 15;
    int b = blockIdx.x >> 6, h = blockIdx.x & 63;

    // ================= Phase A: k1m =================
    {
        auto Bs = (unsigned short (*)[2][4][64][8])(smem + 32768);  // [buf][plane][c4][x][ci8]
        int wm = wid >> 1, wn = wid & 1;
        int xs = t & 63, g4 = t >> 6;              // stage role: x, 4-ci group
        int c4w = g4 >> 1, sub = g4 & 1;
        const float* msb = ms + ((size_t)b * 256 + g4 * 4) * HW + h * 64 + xs;
        for (int i = t; i < 448; i += 512) biasS[i] = bias448[i];
        if (t < 128) biasB[t] = Wv_b[t];
        if (t < 64) lmS[t] = 0.f;

        f32x4 acc[7][2];
#pragma unroll
        for (int mf = 0; mf < 7; ++mf)
#pragma unroll
            for (int nf = 0; nf < 2; ++nf) acc[mf][nf] = (f32x4){0.f, 0.f, 0.f, 0.f};

        const bf16x8* Whip = (const bf16x8*)Wall;
        const bf16x8* Wlop = (const bf16x8*)Wallo;

#define CVT_WRITE(bufv, F0, F1, F2, F3) do {                                    \
        unsigned short h0 = f2b(F0), h1 = f2b(F1), h2 = f2b(F2), h3 = f2b(F3);  \
        unsigned short q0 = f2b((F0) - b2f(h0)), q1 = f2b((F1) - b2f(h1));      \
        unsigned short q2 = f2b((F2) - b2f(h2)), q3 = f2b((F3) - b2f(h3));      \
        uint2 hw, lw;                                                           \
        hw.x = (unsigned)h0 | ((unsigned)h1 << 16);                             \
        hw.y = (unsigned)h2 | ((unsigned)h3 << 16);                             \
        lw.x = (unsigned)q0 | ((unsigned)q1 << 16);                             \
        lw.y = (unsigned)q2 | ((unsigned)q3 << 16);                             \
        *(uint2*)&Bs[bufv][0][c4w][xs][sub * 4] = hw;                           \
        *(uint2*)&Bs[bufv][1][c4w][xs][sub * 4] = lw;                           \
    } while (0)

        {
            float f0 = msb[0], f1 = msb[HW], f2 = msb[2 * HW], f3 = msb[3 * HW];
            CVT_WRITE(0, f0, f1, f2, f3);
        }
        __syncthreads();

        for (int s = 0; s < 8; ++s) {
            int cur = s & 1;
            float fn0, fn1, fn2, fn3;
            if (s < 7) {
                const float* p = msb + (size_t)(s + 1) * 32 * HW;
                fn0 = p[0]; fn1 = p[HW]; fn2 = p[2 * HW]; fn3 = p[3 * HW];
            }
            bf16x8 bh[2], bl[2];
#pragma unroll
            for (int nf = 0; nf < 2; ++nf) {
                int x = wn * 32 + nf * 16 + lrow;
                bh[nf] = *(const bf16x8*)&Bs[cur][0][c4l][x][0];
                bl[nf] = *(const bf16x8*)&Bs[cur][1][c4l][x][0];
            }
#pragma unroll
            for (int mf = 0; mf < 7; ++mf) {
                size_t widx = (size_t)(s * 4 + c4l) * 448 + wm * 112 + mf * 16 + lrow;
                bf16x8 ah = Whip[widx];
                bf16x8 al = Wlop[widx];
#pragma unroll
                for (int nf = 0; nf < 2; ++nf) {
                    acc[mf][nf] = __builtin_amdgcn_mfma_f32_16x16x32_bf16(ah, bh[nf], acc[mf][nf], 0, 0, 0);
                    acc[mf][nf] = __builtin_amdgcn_mfma_f32_16x16x32_bf16(ah, bl[nf], acc[mf][nf], 0, 0, 0);
                    acc[mf][nf] = __builtin_amdgcn_mfma_f32_16x16x32_bf16(al, bh[nf], acc[mf][nf], 0, 0, 0);
                }
            }
            if (s < 7) CVT_WRITE(cur ^ 1, fn0, fn1, fn2, fn3);
            __syncthreads();
        }
#undef CVT_WRITE

        int px0 = wn * 32;
        float lmp[2] = {0.f, 0.f};
#pragma unroll
        for (int mf = 0; mf < 7; ++mf) {
            int base = wm * 112 + mf * 16;
            int r0 = base + c4l * 4;
            if (base < 128) {
#pragma unroll
                for (int nf = 0; nf < 2; ++nf) {
                    int x = px0 + nf * 16 + lrow;
                    f32x4 v = acc[mf][nf];
#pragma unroll
                    for (int j = 0; j < 4; ++j)
                        qtS16[(r0 + j) * 64 + x] = f2b(v[j] + biasS[r0 + j]);
                }
            } else {
                float b0 = biasS[r0], b1 = biasS[r0 + 1], b2 = biasS[r0 + 2], b3 = biasS[r0 + 3];
#pragma unroll
                for (int nf = 0; nf < 2; ++nf) {
                    f32x4 v = acc[mf][nf];
                    lmp[nf] += (v[0] + b0) * (v[1] + b1) + (v[2] + b2) * (v[3] + b3);
                }
            }
        }
        if (wm != 0) {
#pragma unroll
            for (int nf = 0; nf < 2; ++nf) {
                lmp[nf] += __shfl_xor(lmp[nf], 16);
                lmp[nf] += __shfl_xor(lmp[nf], 32);
            }
            if (c4l == 0) {
#pragma unroll
                for (int nf = 0; nf < 2; ++nf)
                    atomicAdd(&lmS[px0 + nf * 16 + lrow], lmp[nf]);
            }
        }
    }

    // ================= Phase B: k2m =================
    {
        auto Bs = (unsigned short (*)[6336])(smem + 32768);   // [buf][792 chunks * 8]
        int wm = wid >> 1, wn = wid & 1;

        f32x4 acc[2][2];
#pragma unroll
        for (int mf = 0; mf < 2; ++mf)
#pragma unroll
            for (int nf = 0; nf < 2; ++nf) acc[mf][nf] = (f32x4){0.f, 0.f, 0.f, 0.f};

        const bf16x8* Wbp = (const bf16x8*)Wb;

#define STAGE2(bufv, sv) do {                                                       \
        for (int iter = 0; iter < 2; ++iter) {                                      \
            int q0 = iter * 512 + (wid << 6);                                       \
            int q = q0 + lane;                                                      \
            if (q < 792) {                                                          \
                int rc = q / 66; int x = q - rc * 66;                               \
                int r = rc >> 2, c4 = rc & 3;                                       \
                int y = h + r;                      /* msP rows h-1..h+1 */         \
                const unsigned short* gp = msP +                                    \
                    (((((size_t)b * 66 + y) * 32) + ((sv) * 4 + c4)) * 66 + x) * 8; \
                unsigned short* lp = &Bs[bufv][q0 * 8];                             \
                __builtin_amdgcn_global_load_lds(                                   \
                    (const __attribute__((address_space(1))) void*)gp,              \
                    (__attribute__((address_space(3))) void*)lp, 16, 0, 0);         \
            }                                                                       \
        }                                                                           \
    } while (0)

        STAGE2(0, 0);
        __syncthreads();

        for (int s = 0; s < 8; ++s) {
            int cur = s & 1;
            if (s < 7) STAGE2(cur ^ 1, s + 1);
#pragma unroll
            for (int khw = 0; khw < 9; ++khw) {
                int kh = khw / 3, kw = khw - 3 * (khw / 3);
                bf16x8 a[2];
#pragma unroll
                for (int mf = 0; mf < 2; ++mf)
                    a[mf] = Wbp[((khw * 8 + s) * 4 + c4l) * 128 + wm * 32 + mf * 16 + lrow];
                bf16x8 bf[2];
#pragma unroll
                for (int nf = 0; nf < 2; ++nf) {
                    int chunk = (kh * 4 + c4l) * 66 + wn * 32 + nf * 16 + lrow + kw;
                    bf[nf] = *(const bf16x8*)&Bs[cur][chunk * 8];
                }
#pragma unroll
                for (int mf = 0; mf < 2; ++mf)
#pragma unroll
                    for (int nf = 0; nf < 2; ++nf)
                        acc[mf][nf] = __builtin_amdgcn_mfma_f32_16x16x32_bf16(
                            a[mf], bf[nf], acc[mf][nf], 0, 0, 0);
            }
            __syncthreads();
        }
#undef STAGE2

#pragma unroll
        for (int mf = 0; mf < 2; ++mf) {
            int co0 = wm * 32 + mf * 16 + c4l * 4;
#pragma unroll
            for (int nf = 0; nf < 2; ++nf) {
                int x = wn * 32 + nf * 16 + lrow;
                f32x4 v = acc[mf][nf];
#pragma unroll
                for (int j = 0; j < 4; ++j)
                    vS16[(co0 + j) * 64 + x] = f2b(v[j] + biasB[co0 + j]);
            }
        }
    }

    // ================= Phase C: online-softmax combine =================
    __syncthreads();   // qtS, vS, lmS all visible
    {
        const unsigned* qtS32 = (const unsigned*)qtS16;
        const unsigned* vS32  = (const unsigned*)vS16;
        int xg = t & 31, cq = t >> 5;     // 32 x-groups of 4, 16 c-groups of 8
        int wv = t >> 6;
        unsigned qp[8], vp[8];
#pragma unroll
        for (int j = 0; j < 8; ++j) {
            qp[j] = qtS32[(cq * 8 + j) * 32 + xg];
            vp[j] = vS32[(cq * 8 + j) * 32 + xg];
        }
        float lmx0 = lmS[xg * 2], lmx1 = lmS[xg * 2 + 1];

        for (int yi = 0; yi < 2; ++yi) {
            int y = 2 * h + yi;
            float m[4] = {lmx0, lmx0, lmx1, lmx1};
            float sum[4] = {1.f, 1.f, 1.f, 1.f};
            float4 oa[8];
#pragma unroll
            for (int j = 0; j < 8; ++j) {
                float vx = b2f((unsigned short)(vp[j] & 0xffffu));
                float vy = b2f((unsigned short)(vp[j] >> 16));
                oa[j] = (float4){vx, vx, vy, vy};
            }
#pragma unroll 1
            for (int n = 0; n < 3; ++n) {
                const float* cb = ctx + ((size_t)(n * 8 + b) * 128 + cq * 8) * YX
                                  + (size_t)y * 128 + xg * 4;
                float4 cx[8];
#pragma unroll
                for (int j = 0; j < 8; ++j) cx[j] = *(const float4*)&cb[(size_t)j * YX];
                float lp[4] = {0.f, 0.f, 0.f, 0.f};
#pragma unroll
                for (int j = 0; j < 8; ++j) {
                    float qx = b2f((unsigned short)(qp[j] & 0xffffu));
                    float qy = b2f((unsigned short)(qp[j] >> 16));
                    lp[0] += cx[j].x * qx;
                    lp[1] += cx[j].y * qx;
                    lp[2] += cx[j].z * qy;
                    lp[3] += cx[j].w * qy;
                }
#pragma unroll
                for (int xl = 0; xl < 4; ++xl) lp[xl] += __shfl_xor(lp[xl], 32);
                __syncthreads();   // prior logitS reads / part usage complete
                if (lane < 32) {
#pragma unroll
                    for (int xl = 0; xl < 4; ++xl) part[wv][xg * 4 + xl] = lp[xl];
                }
                __syncthreads();
                if (t < 128) {
                    float s = 0.f;
#pragma unroll
                    for (int w = 0; w < 8; ++w) s += part[w][t];
                    logitS[t] = s;
                }
                __syncthreads();
                float f[4], e[4];
#pragma unroll
                for (int xl = 0; xl < 4; ++xl) {
                    float ln = logitS[xg * 4 + xl];
                    float nm = fmaxf(m[xl], ln);
                    f[xl] = __expf(m[xl] - nm);
                    e[xl] = __expf(ln - nm);
                    sum[xl] = sum[xl] * f[xl] + e[xl];
                    m[xl] = nm;
                }
#pragma unroll
                for (int j = 0; j < 8; ++j) {
                    oa[j].x = oa[j].x * f[0] + e[0] * cx[j].x;
                    oa[j].y = oa[j].y * f[1] + e[1] * cx[j].y;
                    oa[j].z = oa[j].z * f[2] + e[2] * cx[j].z;
                    oa[j].w = oa[j].w * f[3] + e[3] * cx[j].w;
                }
            }
            float r0 = 1.f / sum[0], r1 = 1.f / sum[1], r2 = 1.f / sum[2], r3 = 1.f / sum[3];
            float* obase = out + ((size_t)b * 128 + cq * 8) * YX + (size_t)y * 128 + xg * 4;
#pragma unroll
            for (int j = 0; j < 8; ++j) {
                float4 o;
                o.x = oa[j].x * r0;
                o.y = oa[j].y * r1;
                o.z = oa[j].z * r2;
                o.w = oa[j].w * r3;
                *(float4*)&obase[(size_t)j * YX] = o;
            }
        }
    }
}

extern "C" void kernel_launch(void* const* d_in, const int* in_sizes, int n_in,
                              void* d_out, int out_size, void* d_ws, size_t ws_size,
                              hipStream_t stream) {
    const float* ctx  = (const float*)d_in[0];
    const float* ms   = (const float*)d_in[1];
    const float* Wc_w = (const float*)d_in[2];
    const float* Wc_b = (const float*)d_in[3];
    const float* Wf_w = (const float*)d_in[4];
    const float* Wf_b = (const float*)d_in[5];
    const float* Wk_w = (const float*)d_in[6];
    const float* Wk_b = (const float*)d_in[7];
    const float* Wv_w = (const float*)d_in[8];
    const float* Wv_b = (const float*)d_in[9];
    float* out = (float*)d_out;
    float* ws = (float*)d_ws;
    float* bias448 = ws + WS_BIAS;
    unsigned short* Wallp  = (unsigned short*)(ws + WS_WALL);
    unsigned short* Wallop = (unsigned short*)(ws + WS_WALLO);
    unsigned short* msPp   = (unsigned short*)(ws + WS_MSP);
    unsigned short* Wbp    = (unsigned short*)(ws + WS_WB);

    hipLaunchKernelGGL(k0, dim3(5956), dim3(256), 0, stream, Wc_w, Wc_b, Wf_w, Wf_b,
                       Wk_w, Wk_b, Wv_w, ms, Wallp, Wallop, bias448, Wbp, msPp);
    hipLaunchKernelGGL(kfull, dim3(512), dim3(512), 0, stream, ms, msPp, Wallp, Wallop,
                       bias448, Wbp, Wv_b, ctx, out);
}